// Round 1
// baseline (166.740 us; speedup 1.0000x reference)
//
#include <hip/hip_runtime.h>
#include <math.h>

// Problem constants
constexpr int NB  = 16;    // batch
constexpr int NH  = 50;    // history
constexpr int NS  = 512;   // signals
constexpr int ND  = 256;   // dim
constexpr int NK  = 8;     // top-k
constexpr int SM1 = NS - 1;            // 511 candidate positions
constexpr int ROWS = NH * (NK + 1) - 1; // 449 output rows per batch
constexpr int HB  = 5;     // h-values per block in query kernel

// ---------------------------------------------------------------------------
// Kernel 1: queries qn[b*NH+h][d] = l2norm( [user(b) ; news_repr(b,h)] @ W^T + bias )
// grid = NB * (NH/HB) blocks, 256 threads. Thread t owns output dim d=t.
// ---------------------------------------------------------------------------
__global__ __launch_bounds__(256) void query_kernel(
    const float* __restrict__ user,      // (NB, 1, ND)
    const float* __restrict__ news_repr, // (NB, NH, ND)
    const float* __restrict__ W,         // (ND, 2*ND) row-major
    const float* __restrict__ bal,       // (ND)
    float* __restrict__ qn)              // (NB*NH, ND)
{
    __shared__ float us[ND];
    __shared__ float nr[HB][ND];
    __shared__ float red[4];

    const int blk = blockIdx.x;
    const int b   = blk / (NH / HB);
    const int h0  = (blk % (NH / HB)) * HB;
    const int tid = threadIdx.x;
    const int lane = tid & 63, wv = tid >> 6;

    us[tid] = user[b * ND + tid];
    #pragma unroll
    for (int i = 0; i < HB; ++i)
        nr[i][tid] = news_repr[((size_t)(b * NH + h0 + i)) * ND + tid];
    __syncthreads();

    const int d = tid;
    const float* wrow = W + (size_t)d * (2 * ND);
    float accu = bal[d];
    float acc[HB];
    #pragma unroll
    for (int i = 0; i < HB; ++i) acc[i] = 0.f;

    for (int e = 0; e < ND; ++e) {
        float w1 = wrow[e];
        accu += w1 * us[e];
        float w2 = wrow[ND + e];
        #pragma unroll
        for (int i = 0; i < HB; ++i) acc[i] += w2 * nr[i][e];
    }

    // normalize each of the HB queries (reduce sumsq across 256 threads)
    for (int i = 0; i < HB; ++i) {
        float q  = accu + acc[i];
        float sq = q * q;
        #pragma unroll
        for (int m = 1; m < 64; m <<= 1) sq += __shfl_xor(sq, m, 64);
        if (lane == 0) red[wv] = sq;
        __syncthreads();
        float tot = red[0] + red[1] + red[2] + red[3];
        __syncthreads();
        float n = fmaxf(sqrtf(tot), 1e-12f);
        qn[((size_t)(b * NH + h0 + i)) * ND + d] = q / n;
    }
}

// ---------------------------------------------------------------------------
// Kernel 2: per-(b,h) block. Scores (cosine) for 511 candidates, masked top-8,
// softmax, gather+scale+order-add, sep row, mask row, kid row.
// grid = NB*NH blocks, 256 threads (4 waves).
// ---------------------------------------------------------------------------
__global__ __launch_bounds__(256) void main_kernel(
    const float* __restrict__ sel,     // (NB,NH,NS,ND) news_selection_embedding
    const float* __restrict__ emb,     // (NB,NH,NS,ND) news_embedding
    const int*   __restrict__ attn,    // (NB,NH,NS)
    const int*   __restrict__ refined, // (NB,NH,NS)
    const float* __restrict__ qn,      // (NB*NH, ND) normalized queries
    const float* __restrict__ sep,     // (ND)
    const float* __restrict__ orde,    // (NH, 1, ND)
    float* __restrict__ out_terms,     // (NB, ROWS, ND)
    float* __restrict__ out_mask,      // (NB, ROWS)
    float* __restrict__ out_kid)       // (NB, NH, NK) as float
{
    __shared__ float sc[SM1];
    __shared__ int   rmask[NS];
    __shared__ float rv[4];
    __shared__ int   ri[4];
    __shared__ int   kid_s[NK];
    __shared__ float soft[NK];

    const int bh  = blockIdx.x;
    const int b   = bh / NH, h = bh % NH;
    const int tid = threadIdx.x;
    const int lane = tid & 63, wv = tid >> 6;

    // stage refined mask (512 ints)
    rmask[tid]       = refined[(size_t)bh * NS + tid];
    rmask[tid + 256] = refined[(size_t)bh * NS + tid + 256];

    // per-lane query fragment (4 consecutive dims), same for all 4 waves
    const float4 q4 = *(const float4*)(qn + (size_t)bh * ND + lane * 4);
    __syncthreads();

    // ---- scores: wave w handles candidates j = w, w+4, ... (s = j+1) ----
    for (int j = wv; j < SM1; j += 4) {
        const int s = j + 1;
        const float4 v = *(const float4*)(sel + ((size_t)bh * NS + s) * ND + lane * 4);
        float dot = v.x * q4.x + v.y * q4.y + v.z * q4.z + v.w * q4.w;
        float nrm = v.x * v.x + v.y * v.y + v.z * v.z + v.w * v.w;
        #pragma unroll
        for (int m = 1; m < 64; m <<= 1) {
            dot += __shfl_xor(dot, m, 64);
            nrm += __shfl_xor(nrm, m, 64);
        }
        if (lane == 0) {
            float score = dot / fmaxf(sqrtf(nrm), 1e-12f);
            if (j >= NK && rmask[s] == 0) score = -INFINITY;
            sc[j] = score;
        }
    }
    __syncthreads();

    // ---- top-8, jax tie-break (equal value -> lower index), descending ----
    for (int k = 0; k < NK; ++k) {
        float bvv = -INFINITY;
        int   bii = 0x7fffffff;
        for (int j = tid; j < SM1; j += 256) {
            float v = sc[j];
            if (v > bvv) { bvv = v; bii = j; }   // ascending scan keeps lower idx on ties
        }
        #pragma unroll
        for (int m = 1; m < 64; m <<= 1) {
            float ov = __shfl_xor(bvv, m, 64);
            int   oi = __shfl_xor(bii, m, 64);
            if (ov > bvv || (ov == bvv && oi < bii)) { bvv = ov; bii = oi; }
        }
        if (lane == 0) { rv[wv] = bvv; ri[wv] = bii; }
        __syncthreads();
        if (tid == 0) {
            float bv2 = rv[0]; int bi2 = ri[0];
            #pragma unroll
            for (int w = 1; w < 4; ++w)
                if (rv[w] > bv2 || (rv[w] == bv2 && ri[w] < bi2)) { bv2 = rv[w]; bi2 = ri[w]; }
            kid_s[k] = bi2;
            soft[k]  = bv2;          // stash raw top value
            sc[bi2]  = -INFINITY;    // remove for next iteration
        }
        __syncthreads();
    }

    // ---- softmax over the 8 (descending) values ----
    if (tid == 0) {
        float mx = soft[0];
        float ex[NK], ssum = 0.f;
        #pragma unroll
        for (int k = 0; k < NK; ++k) { ex[k] = expf(soft[k] - mx); ssum += ex[k]; }
        #pragma unroll
        for (int k = 0; k < NK; ++k) soft[k] = ex[k] / ssum;
    }
    __syncthreads();

    // ---- outputs ----
    const int d = tid;
    const float ordv = orde[h * ND + d];
    float* obase = out_terms + ((size_t)b * ROWS + h * (NK + 1)) * ND;
    #pragma unroll
    for (int k = 0; k < NK; ++k) {
        const int s = kid_s[k] + 1;
        const float e = emb[((size_t)bh * NS + s) * ND + d];
        obase[k * ND + d] = e * soft[k] + ordv;
    }
    const bool has_sep = (h * (NK + 1) + NK) < ROWS;  // h < 49
    if (has_sep) obase[NK * ND + d] = sep[d];

    if (tid < NK) {
        const int s = kid_s[tid] + 1;
        out_mask[(size_t)b * ROWS + h * (NK + 1) + tid] = (float)attn[(size_t)bh * NS + s];
        out_kid[(size_t)bh * NK + tid] = (float)kid_s[tid];
    }
    if (tid == NK && has_sep)
        out_mask[(size_t)b * ROWS + h * (NK + 1) + NK] = 1.0f;
}

// ---------------------------------------------------------------------------
extern "C" void kernel_launch(void* const* d_in, const int* in_sizes, int n_in,
                              void* d_out, int out_size, void* d_ws, size_t ws_size,
                              hipStream_t stream) {
    const float* sel   = (const float*)d_in[0];
    const float* emb   = (const float*)d_in[1];
    const float* user  = (const float*)d_in[2];
    const float* nrp   = (const float*)d_in[3];
    const int*   attn  = (const int*)d_in[4];
    const int*   refin = (const int*)d_in[5];
    const float* W     = (const float*)d_in[6];
    const float* bal   = (const float*)d_in[7];
    const float* sep   = (const float*)d_in[8];
    const float* orde  = (const float*)d_in[9];

    float* qn = (float*)d_ws;  // NB*NH*ND floats = 800 KB scratch

    float* out_terms = (float*)d_out;
    float* out_mask  = out_terms + (size_t)NB * ROWS * ND;
    float* out_kid   = out_mask + (size_t)NB * ROWS;

    query_kernel<<<NB * (NH / HB), 256, 0, stream>>>(user, nrp, W, bal, qn);
    main_kernel<<<NB * NH, 256, 0, stream>>>(sel, emb, attn, refin, qn, sep, orde,
                                             out_terms, out_mask, out_kid);
}

// Round 2
// 117.447 us; speedup vs baseline: 1.4197x; 1.4197x over previous
//
#include <hip/hip_runtime.h>
#include <math.h>

// Problem constants
constexpr int NB  = 16;    // batch
constexpr int NH  = 50;    // history
constexpr int NS  = 512;   // signals
constexpr int ND  = 256;   // dim
constexpr int NK  = 8;     // top-k
constexpr int SM1 = NS - 1;             // 511 candidate positions
constexpr int ROWS = NH * (NK + 1) - 1; // 449 output rows per batch
constexpr int HB  = 5;     // h-values per block in query kernel
constexpr int CHUNKS = 4;  // score chunks per (b,h)
constexpr int RPC = 128;   // rows per chunk (last chunk has 127)

// ---------------------------------------------------------------------------
// Kernel 1: queries qn[b*NH+h][d] = l2norm( [user(b) ; news_repr(b,h)] @ W^T + bias )
// grid = NB * (NH/HB) blocks, 256 threads. Thread t owns output dim d=t.
// ---------------------------------------------------------------------------
__global__ __launch_bounds__(256) void query_kernel(
    const float* __restrict__ user,      // (NB, 1, ND)
    const float* __restrict__ news_repr, // (NB, NH, ND)
    const float* __restrict__ W,         // (ND, 2*ND) row-major
    const float* __restrict__ bal,       // (ND)
    float* __restrict__ qn)              // (NB*NH, ND)
{
    __shared__ float us[ND];
    __shared__ float nr[HB][ND];
    __shared__ float red[4];

    const int blk = blockIdx.x;
    const int b   = blk / (NH / HB);
    const int h0  = (blk % (NH / HB)) * HB;
    const int tid = threadIdx.x;
    const int lane = tid & 63, wv = tid >> 6;

    us[tid] = user[b * ND + tid];
    #pragma unroll
    for (int i = 0; i < HB; ++i)
        nr[i][tid] = news_repr[((size_t)(b * NH + h0 + i)) * ND + tid];
    __syncthreads();

    const int d = tid;
    const float* wrow = W + (size_t)d * (2 * ND);
    float accu = bal[d];
    float acc[HB];
    #pragma unroll
    for (int i = 0; i < HB; ++i) acc[i] = 0.f;

    for (int e = 0; e < ND; ++e) {
        float w1 = wrow[e];
        accu += w1 * us[e];
        float w2 = wrow[ND + e];
        #pragma unroll
        for (int i = 0; i < HB; ++i) acc[i] += w2 * nr[i][e];
    }

    // normalize each of the HB queries (reduce sumsq across 256 threads)
    for (int i = 0; i < HB; ++i) {
        float q  = accu + acc[i];
        float sq = q * q;
        #pragma unroll
        for (int m = 1; m < 64; m <<= 1) sq += __shfl_xor(sq, m, 64);
        if (lane == 0) red[wv] = sq;
        __syncthreads();
        float tot = red[0] + red[1] + red[2] + red[3];
        __syncthreads();
        float n = fmaxf(sqrtf(tot), 1e-12f);
        qn[((size_t)(b * NH + h0 + i)) * ND + d] = q / n;
    }
}

// ---------------------------------------------------------------------------
// Kernel 2: scores. grid = NB*NH*CHUNKS blocks, 256 threads.
// Each 16-lane quarter-wave computes one candidate row's cosine score:
// 4 float4 loads (coalesced 256B segments), 4-level width-16 shuffle reduce.
// Writes RAW scores (no mask) to scw[bh*NS + j], j in [0, 511).
// ---------------------------------------------------------------------------
__global__ __launch_bounds__(256) void score_kernel(
    const float* __restrict__ sel,  // (NB,NH,NS,ND)
    const float* __restrict__ qn,   // (NB*NH, ND)
    float* __restrict__ scw)        // (NB*NH, NS)
{
    const int blk   = blockIdx.x;
    const int bh    = blk >> 2;     // / CHUNKS
    const int chunk = blk & (CHUNKS - 1);
    const int j0    = chunk * RPC;
    const int tid   = threadIdx.x;
    const int ql    = tid & 15;     // lane within quarter
    const int q     = tid >> 4;     // quarter id 0..15

    // query fragment matching the row-read pattern: floats [i*64 + ql*4 .. +3]
    float4 qf[4];
    #pragma unroll
    for (int i = 0; i < 4; ++i)
        qf[i] = *(const float4*)(qn + (size_t)bh * ND + i * 64 + ql * 4);

    const float* base_bh = sel + (size_t)bh * NS * ND;

    for (int jj = q; jj < RPC; jj += 16) {
        const int j = j0 + jj;
        if (j >= SM1) break;
        const float* row = base_bh + (size_t)(j + 1) * ND;
        float dot = 0.f, nrm = 0.f;
        #pragma unroll
        for (int i = 0; i < 4; ++i) {
            const float4 v = *(const float4*)(row + i * 64 + ql * 4);
            dot += v.x * qf[i].x + v.y * qf[i].y + v.z * qf[i].z + v.w * qf[i].w;
            nrm += v.x * v.x + v.y * v.y + v.z * v.z + v.w * v.w;
        }
        #pragma unroll
        for (int m = 1; m < 16; m <<= 1) {
            dot += __shfl_xor(dot, m, 16);
            nrm += __shfl_xor(nrm, m, 16);
        }
        if (ql == 0)
            scw[(size_t)bh * NS + j] = dot / fmaxf(sqrtf(nrm), 1e-12f);
    }
}

// ---------------------------------------------------------------------------
// Kernel 3: per-wave top-8 + softmax + gather/write. One wave per (b,h).
// grid = NB*NH/4 blocks, 256 threads (4 waves).
// ---------------------------------------------------------------------------
__global__ __launch_bounds__(256) void topk_out_kernel(
    const float* __restrict__ emb,     // (NB,NH,NS,ND)
    const int*   __restrict__ attn,    // (NB,NH,NS)
    const int*   __restrict__ refined, // (NB,NH,NS)
    const float* __restrict__ scw,     // (NB*NH, NS) raw scores
    const float* __restrict__ sep,     // (ND)
    const float* __restrict__ orde,    // (NH, 1, ND)
    float* __restrict__ out_terms,     // (NB, ROWS, ND)
    float* __restrict__ out_mask,      // (NB, ROWS)
    float* __restrict__ out_kid)       // (NB, NH, NK) as float
{
    __shared__ int rm[4][NS];
    const int tid  = threadIdx.x;
    const int wv   = tid >> 6, lane = tid & 63;
    const int bh0  = blockIdx.x * 4;

    // stage refined masks for the block's 4 bh (coalesced)
    for (int idx = tid; idx < 4 * NS; idx += 256)
        rm[idx >> 9][idx & (NS - 1)] =
            refined[(size_t)(bh0 + (idx >> 9)) * NS + (idx & (NS - 1))];
    __syncthreads();

    const int bh = bh0 + wv;
    const int b  = bh / NH, h = bh % NH;

    // each lane owns 8 candidate scores
    float v[8];
    {
        const float4 a = *(const float4*)(scw + (size_t)bh * NS + lane * 8);
        const float4 c = *(const float4*)(scw + (size_t)bh * NS + lane * 8 + 4);
        v[0] = a.x; v[1] = a.y; v[2] = a.z; v[3] = a.w;
        v[4] = c.x; v[5] = c.y; v[6] = c.z; v[7] = c.w;
    }
    #pragma unroll
    for (int t = 0; t < 8; ++t) {
        const int j = lane * 8 + t;
        if (j >= SM1)                              v[t] = -INFINITY;
        else if (j >= NK && rm[wv][j + 1] == 0)    v[t] = -INFINITY;
    }

    // iterative top-8, all in-wave; jax tie-break (equal value -> lower index)
    float topv[NK];
    int   topi[NK];
    int   myi = 0;   // lane k keeps topi[k] for the mask/kid writes
    #pragma unroll
    for (int k = 0; k < NK; ++k) {
        float bv = -INFINITY; int bi = 0x7fffffff;
        #pragma unroll
        for (int t = 0; t < 8; ++t)
            if (v[t] > bv) { bv = v[t]; bi = lane * 8 + t; }  // ascending t keeps lower idx
        #pragma unroll
        for (int m = 1; m < 64; m <<= 1) {
            const float ov = __shfl_xor(bv, m, 64);
            const int   oi = __shfl_xor(bi, m, 64);
            if (ov > bv || (ov == bv && oi < bi)) { bv = ov; bi = oi; }
        }
        topv[k] = bv; topi[k] = bi;          // identical in all lanes
        if (lane == k) myi = bi;
        #pragma unroll
        for (int t = 0; t < 8; ++t)          // static indexing (no scratch)
            if (lane * 8 + t == bi) v[t] = -INFINITY;
    }

    // softmax over the 8 (descending) values, replicated per lane
    float wk[NK], ssum = 0.f;
    #pragma unroll
    for (int k = 0; k < NK; ++k) { wk[k] = expf(topv[k] - topv[0]); ssum += wk[k]; }
    const float inv = 1.f / ssum;

    // outputs: lane handles 4 consecutive dims per row
    const int d4 = lane * 4;
    const float4 ord4 = *(const float4*)(orde + (size_t)h * ND + d4);
    float* obase = out_terms + ((size_t)b * ROWS + h * (NK + 1)) * ND;
    #pragma unroll
    for (int k = 0; k < NK; ++k) {
        const int s = topi[k] + 1;
        const float4 e = *(const float4*)(emb + ((size_t)bh * NS + s) * ND + d4);
        const float w = wk[k] * inv;
        float4 o;
        o.x = e.x * w + ord4.x;
        o.y = e.y * w + ord4.y;
        o.z = e.z * w + ord4.z;
        o.w = e.w * w + ord4.w;
        *(float4*)(obase + k * ND + d4) = o;
    }
    const bool has_sep = h < NH - 1;
    if (has_sep)
        *(float4*)(obase + NK * ND + d4) = *(const float4*)(sep + d4);

    if (lane < NK) {
        out_mask[(size_t)b * ROWS + h * (NK + 1) + lane] =
            (float)attn[(size_t)bh * NS + myi + 1];
        out_kid[(size_t)bh * NK + lane] = (float)myi;
    }
    if (lane == NK && has_sep)
        out_mask[(size_t)b * ROWS + h * (NK + 1) + NK] = 1.0f;
}

// ---------------------------------------------------------------------------
extern "C" void kernel_launch(void* const* d_in, const int* in_sizes, int n_in,
                              void* d_out, int out_size, void* d_ws, size_t ws_size,
                              hipStream_t stream) {
    const float* sel   = (const float*)d_in[0];
    const float* emb   = (const float*)d_in[1];
    const float* user  = (const float*)d_in[2];
    const float* nrp   = (const float*)d_in[3];
    const int*   attn  = (const int*)d_in[4];
    const int*   refin = (const int*)d_in[5];
    const float* W     = (const float*)d_in[6];
    const float* bal   = (const float*)d_in[7];
    const float* sep   = (const float*)d_in[8];
    const float* orde  = (const float*)d_in[9];

    float* qn  = (float*)d_ws;                       // NB*NH*ND floats (800 KB)
    float* scw = qn + (size_t)NB * NH * ND;          // NB*NH*NS floats (1.6 MB)

    float* out_terms = (float*)d_out;
    float* out_mask  = out_terms + (size_t)NB * ROWS * ND;
    float* out_kid   = out_mask + (size_t)NB * ROWS;

    query_kernel<<<NB * (NH / HB), 256, 0, stream>>>(user, nrp, W, bal, qn);
    score_kernel<<<NB * NH * CHUNKS, 256, 0, stream>>>(sel, qn, scw);
    topk_out_kernel<<<NB * NH / 4, 256, 0, stream>>>(emb, attn, refin, scw, sep, orde,
                                                     out_terms, out_mask, out_kid);
}